// Round 7
// baseline (116.992 us; speedup 1.0000x reference)
//
#include <hip/hip_runtime.h>
#include <hip/hip_bf16.h>

#define T_SEQ 2048
#define NH 16
#define HD 64
// 0.1 (attn scale) * log2(e) folded into q at norm time -> softmax uses exp2
#define SCALE_LOG2E 0.14426950408889634f

typedef __attribute__((ext_vector_type(8))) short bf16x8;
typedef __attribute__((ext_vector_type(4))) short bf16x4;
typedef __attribute__((ext_vector_type(4))) float f32x4;

__device__ __forceinline__ short f2bs(float f) {
  union { float f; unsigned u; } v; v.f = f;
  unsigned r = v.u + 0x7fffu + ((v.u >> 16) & 1u);
  return (short)(r >> 16);
}

__device__ __forceinline__ unsigned cvt_pk_bf16(float lo, float hi) {
  unsigned r;
  asm("v_cvt_pk_bf16_f32 %0, %1, %2" : "=v"(r) : "v"(lo), "v"(hi));
  return r;
}

__device__ __forceinline__ void gload16(const short* g, short* l) {
  __builtin_amdgcn_global_load_lds(
      (const __attribute__((address_space(1))) void*)g,
      (__attribute__((address_space(3))) void*)l, 16, 0, 0);
}

// ---------------- fused f32 -> bf16 convert (x, Wq|Wk|Wv, Wproj) ----------------
__global__ __launch_bounds__(256) void cvt_all(const float* __restrict__ x,
                                               const float* __restrict__ wq,
                                               const float* __restrict__ wk,
                                               const float* __restrict__ wv,
                                               const float* __restrict__ wp,
                                               short* __restrict__ xb,
                                               short* __restrict__ wqkv,
                                               short* __restrict__ wpj) {
  size_t i4 = (size_t)(blockIdx.x * 256 + threadIdx.x) * 4;  // over 6M elements
  const int seg = (int)(i4 >> 20);
  const size_t off = i4 & ((1u << 20) - 1);
  const float* src;
  short* dst;
  if (seg < 2)       { src = x + i4;   dst = xb + i4; }
  else if (seg == 2) { src = wq + off; dst = wqkv + off; }
  else if (seg == 3) { src = wk + off; dst = wqkv + (1u << 20) + off; }
  else if (seg == 4) { src = wv + off; dst = wqkv + (2u << 20) + off; }
  else               { src = wp + off; dst = wpj + off; }
  float4 v = *reinterpret_cast<const float4*>(src);
  bf16x4 o; o[0] = f2bs(v.x); o[1] = f2bs(v.y); o[2] = f2bs(v.z); o[3] = f2bs(v.w);
  *reinterpret_cast<bf16x4*>(dst) = o;
}

// -------- gate: sigmoid(x[:, :12] @ Wgate^T); also fills rope table (cos,sin) --------
__global__ __launch_bounds__(256) void gate_rope(const float* __restrict__ x,
                                                 const float* __restrict__ Wg,
                                                 float* __restrict__ gate,
                                                 float2* __restrict__ rope) {
  int id = blockIdx.x * 256 + threadIdx.x;  // t*16 + h, 32768 total
  int t = id >> 4, h = id & 15;
  float acc = 0.f;
  #pragma unroll
  for (int i = 0; i < 12; ++i) acc += x[(size_t)t * 1024 + i] * Wg[h * 12 + i];
  gate[id] = 1.f / (1.f + __expf(-acc));
  // rope[t][p]: 65536 entries, 2 per thread
  #pragma unroll
  for (int j = 0; j < 2; ++j) {
    int e = id * 2 + j;
    int tt = e >> 5, p = e & 31;
    float invf = __builtin_exp2f(-0.41524101186092f * (float)p);
    float s, c;
    sincosf((float)tt * invf, &s, &c);
    rope[e] = make_float2(c, s);
  }
}

// ---------------- GEMM: C[M][N] = A[M][K] * B[N][K]^T (bf16 in) ----------------
// BM=64 x BN tile, BK=32, 4 waves (2x2); TRIPLE-buffered global_load_lds staging with
// COUNTED vmcnt (T4): per wave per step exactly L loads (L=1+BN/64, uniform across
// waves), depth-2 prefetch; s_waitcnt vmcnt(L) at step top waits only the tile being
// consumed while the next stage stays in flight ACROSS the raw s_barrier (never
// drain to 0 in the loop - the round-6 __syncthreads drained vmcnt(0) every step and
// exposed ~300cy/step). Slot reuse safe: stage@k writes slot (k+2)%3=(k-1)%3 whose
// ds_reads completed (consumed by MFMAs) before readers reached barrier k;
// sched_barrier(0) after s_barrier stops ds_read hoisting (rule #18).
// QKV=true: fused epilogue. bn<2048 -> RMSNorm+RoPE -> bf16 qb/kb [h][t][64];
//           bn>=2048 -> plain f32 Cv (cols bn-2048). QKV=false: plain f32 C.
template <int BN, bool QKV>
__global__ __launch_bounds__(256) void gemm64(const short* __restrict__ A,
                                              const short* __restrict__ B,
                                              float* __restrict__ C,
                                              short* __restrict__ qb,
                                              short* __restrict__ kb,
                                              const float2* __restrict__ rope,
                                              int N, int K) {
  constexpr int NB = BN / 32;  // fragments per wave in N
  __shared__ __attribute__((aligned(16))) short As[3][4][64][8];
  __shared__ __attribute__((aligned(16))) short Bs[3][4][BN][8];
  const int tid = threadIdx.x;
  const int lane = tid & 63, wid = tid >> 6;
  const int lr = lane & 15, lg = lane >> 4;
  const int wm = (wid >> 1) * 32, wn = (wid & 1) * (BN / 2);
  const int bm = blockIdx.x * 64, bn = blockIdx.y * BN;
  // wave `wid` stages k-slot `wid` (k offset wid*8)
  const short* Ap = A + (size_t)(bm + lane) * K + wid * 8;
  const short* Bp = B + (size_t)(bn + lane) * K + wid * 8;
  f32x4 acc[2][NB] = {};
  auto stage = [&](int buf, int k0) {
    gload16(Ap + k0, &As[buf][wid][0][0]);
    #pragma unroll
    for (int g = 0; g < BN / 64; ++g)
      gload16(Bp + (size_t)(64 * g) * K + k0, &Bs[buf][wid][64 * g][0]);
  };
  auto compute = [&](int buf) {
    bf16x8 af[2], bfr[NB];
    #pragma unroll
    for (int m = 0; m < 2; ++m) af[m] = *(const bf16x8*)&As[buf][lg][wm + m * 16 + lr][0];
    #pragma unroll
    for (int n = 0; n < NB; ++n) bfr[n] = *(const bf16x8*)&Bs[buf][lg][wn + n * 16 + lr][0];
    #pragma unroll
    for (int m = 0; m < 2; ++m)
      #pragma unroll
      for (int n = 0; n < NB; ++n)
        acc[m][n] = __builtin_amdgcn_mfma_f32_16x16x32_bf16(af[m], bfr[n], acc[m][n], 0, 0, 0);
  };
  const int nsteps = K >> 5;
  stage(0, 0);
  stage(1, 32);
  int cur = 0;
  for (int ks = 0; ks < nsteps - 1; ++ks) {
    // wait only the oldest stage (L loads); the next stage stays in flight
    if constexpr (BN == 128) asm volatile("s_waitcnt vmcnt(3)" ::: "memory");
    else                     asm volatile("s_waitcnt vmcnt(2)" ::: "memory");
    __builtin_amdgcn_s_barrier();
    __builtin_amdgcn_sched_barrier(0);
    int s2 = cur + 2; if (s2 >= 3) s2 -= 3;
    if (ks + 2 < nsteps) stage(s2, (ks + 2) * 32);
    compute(cur);
    cur = (cur == 2) ? 0 : cur + 1;
  }
  asm volatile("s_waitcnt vmcnt(0)" ::: "memory");
  __builtin_amdgcn_s_barrier();
  __builtin_amdgcn_sched_barrier(0);
  compute(cur);

  if constexpr (QKV) {
    if (bn < 2048) {  // q or k head: wave cols = exactly one head
      const bool isq = (bn < 1024);
      short* dst = isq ? qb : kb;
      const int h = ((bn + wn) & 1023) >> 6;
      #pragma unroll
      for (int m = 0; m < 2; ++m)
        #pragma unroll
        for (int r = 0; r < 4; ++r) {
          const int t = bm + wm + m * 16 + 4 * lg + r;
          float ss = acc[m][0][r] * acc[m][0][r] + acc[m][1][r] * acc[m][1][r]
                   + acc[m][2][r] * acc[m][2][r] + acc[m][3][r] * acc[m][3][r];
          ss += __shfl_xor(ss, 1);
          ss += __shfl_xor(ss, 2);
          ss += __shfl_xor(ss, 4);
          ss += __shfl_xor(ss, 8);
          const float rms = rsqrtf(ss * (1.f / 64.f) + 1e-6f);
          short* row = dst + ((size_t)h * T_SEQ + t) * 64;
          #pragma unroll
          for (int n2 = 0; n2 < 2; ++n2) {  // rope pair (d, d+32) = (n2, n2+2)
            float x1 = acc[m][n2][r] * rms, x2 = acc[m][n2 + 2][r] * rms;
            float2 cs = rope[t * 32 + n2 * 16 + lr];
            float y1 = x1 * cs.x + x2 * cs.y;
            float y2 = x2 * cs.x - x1 * cs.y;
            if (isq) { y1 *= SCALE_LOG2E; y2 *= SCALE_LOG2E; }
            row[n2 * 16 + lr] = f2bs(y1);
            row[32 + n2 * 16 + lr] = f2bs(y2);
          }
        }
    } else {  // v region -> plain f32 Cv [t][1024]
      #pragma unroll
      for (int m = 0; m < 2; ++m)
        #pragma unroll
        for (int r = 0; r < 4; ++r) {
          const int t = bm + wm + m * 16 + 4 * lg + r;
          float* Cr = C + (size_t)t * 1024 + (bn - 2048) + wn + lr;
          #pragma unroll
          for (int n = 0; n < NB; ++n) Cr[n * 16] = acc[m][n][r];
        }
    }
  } else {
    #pragma unroll
    for (int m = 0; m < 2; ++m)
      #pragma unroll
      for (int r = 0; r < 4; ++r) {
        const int t = bm + wm + m * 16 + 4 * lg + r;
        float* Cr = C + (size_t)t * N + bn + wn + lr;
        #pragma unroll
        for (int n = 0; n < NB; ++n) Cr[n * 16] = acc[m][n][r];
      }
  }
}

// ---------------- v blend + transpose to vt[h][hd][kv'] (kv permuted per 32-block) ----
// kv' column c within each 32-block holds actual kv = (c&1)*16 + (c>>1), so that
// attention's P-pack (p_t0, p_t1) lands in adjacent columns.
__global__ __launch_bounds__(256) void v_blend_tr(const float* __restrict__ Cv,
                                                  const float* __restrict__ v1,
                                                  const float* __restrict__ lambp,
                                                  short* __restrict__ vt) {
  __shared__ short lv[128][72];
  const int h = blockIdx.y, t0 = blockIdx.x * 128;
  const float lamb = *lambp;
  const int tid = threadIdx.x;
  #pragma unroll 4
  for (int it = 0; it < 32; ++it) {
    int e = it * 256 + tid;
    int tl = e >> 6, d = e & 63;
    float v = Cv[(size_t)(t0 + tl) * 1024 + h * 64 + d];
    float w = v1[(size_t)(t0 + tl) * 1024 + h * 64 + d];
    lv[tl][d] = f2bs((1.f - lamb) * v + lamb * w);
  }
  __syncthreads();
  #pragma unroll 4
  for (int it = 0; it < 32; ++it) {
    int e = it * 256 + tid;
    int d = e >> 7, tl = e & 127;
    int src = (tl & 96) + ((tl & 1) << 4) + ((tl >> 1) & 15);  // permuted source row
    vt[((size_t)h * 64 + d) * T_SEQ + t0 + tl] = lv[src][d];
  }
}

// ---------------- causal attention, split-KV, LDS-staged K/V (double-buffered) -------
// No online max needed (scores bounded by RMS norm): partials over kv strips combine
// by plain addition of accO and lsum -> split-KV grid (head, qgroup64, strip512).
// Partials stored compactly at slot = head*80 + b (b = linear job id 0..79).
__global__ __launch_bounds__(256) void attn(const short* __restrict__ qb,
                                            const short* __restrict__ kb,
                                            const short* __restrict__ vtp,
                                            float* __restrict__ part) {
  __shared__ __attribute__((aligned(16))) short Ks[2][4096];
  __shared__ __attribute__((aligned(16))) short Vs[2][4096];
  __shared__ __attribute__((aligned(16))) short p_lds[4][16][72];
  const int head = blockIdx.x & 15;
  const int b = blockIdx.x >> 4;  // 0..79
  int strip, qg;  // heavy-first (qg descending) within each strip class
  if (b < 32)      { strip = 0; qg = 31 - b; }
  else if (b < 56) { strip = 1; qg = 63 - b; }   // qg 31..8
  else if (b < 72) { strip = 2; qg = 87 - b; }   // qg 31..16
  else             { strip = 3; qg = 103 - b; }  // qg 31..24
  const int nt = min(8, qg + 1 - strip * 8);
  const int lane = threadIdx.x & 63, wid = threadIdx.x >> 6;
  const int lr = lane & 15, lg = lane >> 4;
  const int qt0 = qg * 64 + wid * 16;
  const short* Q = qb + (size_t)head * (T_SEQ * HD);
  const short* Kp = kb + (size_t)head * (T_SEQ * HD);
  const short* Vt = vtp + (size_t)head * (HD * T_SEQ);
  short (*P)[72] = p_lds[wid];

  bf16x8 aq0 = *(const bf16x8*)&Q[(size_t)(qt0 + lr) * HD + 8 * lg];
  bf16x8 aq1 = *(const bf16x8*)&Q[(size_t)(qt0 + lr) * HD + 32 + 8 * lg];
  f32x4 accO[4] = {};
  float lsum[4] = {0.f, 0.f, 0.f, 0.f};

  auto stage = [&](int buf, int jg) {
    const int kv0 = jg * 64;
    #pragma unroll
    for (int i = 0; i < 2; ++i) {
      int s = i * 256 + wid * 64 + lane;       // chunk id 0..511 (16B chunks)
      int row = s >> 3;                        // tile row 0..63
      int cG = (s & 7) ^ (row & 7);            // inverse-swizzled source chunk
      gload16(Kp + (size_t)(kv0 + row) * HD + cG * 8,
              &Ks[buf][(size_t)(i * 256 + wid * 64) * 8]);
      gload16(Vt + (size_t)row * T_SEQ + kv0 + cG * 8,
              &Vs[buf][(size_t)(i * 256 + wid * 64) * 8]);
    }
  };
  stage(0, strip * 8);
  for (int j = 0; j < nt; ++j) {
    const int jg = strip * 8 + j;
    __syncthreads();                            // drains vmcnt: buf[j&1] ready
    if (j + 1 < nt) stage((j + 1) & 1, jg + 1); // prefetch stays in flight
    const short* Kb = Ks[j & 1];
    const short* Vb = Vs[j & 1];
    f32x4 st[4];
    #pragma unroll
    for (int t = 0; t < 4; ++t) {
      int row = 16 * t + lr;
      int c0 = lg ^ (row & 7);
      bf16x8 k0 = *(const bf16x8*)&Kb[row * 64 + c0 * 8];
      bf16x8 k1 = *(const bf16x8*)&Kb[row * 64 + (c0 ^ 4) * 8];
      f32x4 s = {};
      s = __builtin_amdgcn_mfma_f32_16x16x32_bf16(aq0, k0, s, 0, 0, 0);
      s = __builtin_amdgcn_mfma_f32_16x16x32_bf16(aq1, k1, s, 0, 0, 0);
      st[t] = s;
    }
    if (jg == qg) {  // diagonal tile: causal mask (block-uniform branch)
      #pragma unroll
      for (int t = 0; t < 4; ++t)
        #pragma unroll
        for (int r = 0; r < 4; ++r)
          st[t][r] = (16 * t + lr > wid * 16 + 4 * lg + r) ? -1e30f : st[t][r];
    }
    #pragma unroll
    for (int r = 0; r < 4; ++r) {
      float p0 = __builtin_exp2f(st[0][r]);
      float p1 = __builtin_exp2f(st[1][r]);
      float p2 = __builtin_exp2f(st[2][r]);
      float p3 = __builtin_exp2f(st[3][r]);
      lsum[r] += (p0 + p1) + (p2 + p3);
      *(unsigned*)&P[4 * lg + r][2 * lr] = cvt_pk_bf16(p0, p1);
      *(unsigned*)&P[4 * lg + r][32 + 2 * lr] = cvt_pk_bf16(p2, p3);
    }
    asm volatile("s_waitcnt lgkmcnt(0)" ::: "memory");  // wave-private P roundtrip
    __builtin_amdgcn_sched_barrier(0);
    bf16x8 pa0 = *(const bf16x8*)&P[lr][8 * lg];
    bf16x8 pa1 = *(const bf16x8*)&P[lr][32 + 8 * lg];
    #pragma unroll
    for (int nv = 0; nv < 4; ++nv) {
      int row0 = nv * 16 + lr;
      int c0 = lg ^ (row0 & 7);
      bf16x8 v0 = *(const bf16x8*)&Vb[row0 * 64 + c0 * 8];
      bf16x8 v1 = *(const bf16x8*)&Vb[row0 * 64 + (c0 ^ 4) * 8];
      accO[nv] = __builtin_amdgcn_mfma_f32_16x16x32_bf16(pa0, v0, accO[nv], 0, 0, 0);
      accO[nv] = __builtin_amdgcn_mfma_f32_16x16x32_bf16(pa1, v1, accO[nv], 0, 0, 0);
    }
  }
  // write partials: 64x64 O block + 64 lsum, compact slot = head*80 + b
  float* pO = part + (size_t)(head * 80 + b) * 4160;
  float* pL = pO + 4096;
  #pragma unroll
  for (int r = 0; r < 4; ++r) {
    float sres = lsum[r];
    sres += __shfl_xor(sres, 1);
    sres += __shfl_xor(sres, 2);
    sres += __shfl_xor(sres, 4);
    sres += __shfl_xor(sres, 8);
    int row = wid * 16 + 4 * lg + r;
    #pragma unroll
    for (int nv = 0; nv < 4; ++nv)
      pO[row * 64 + nv * 16 + lr] = accO[nv][r];
    if (lr == 0) pL[row] = sres;
  }
}

// ---------------- combine split-KV partials, apply gate, write bf16 ----------------
__global__ __launch_bounds__(256) void attn_reduce(const float* __restrict__ part,
                                                   const float* __restrict__ gate,
                                                   short* __restrict__ ob) {
  const int head = blockIdx.x & 15;
  const int qg = blockIdx.x >> 4;
  const int ns = (qg >> 3) + 1;
  const int tid = threadIdx.x;
  const int row = tid >> 2, q4 = tid & 3;
  const int sbase[4] = {0, 32, 56, 72};  // strip -> b base (b = sbase[s] + 31 - qg)
  f32x4 o[4] = {};
  float l = 0.f;
  for (int s = 0; s < ns; ++s) {
    const float* pb = part + (size_t)(head * 80 + sbase[s] + 31 - qg) * 4160;
    #pragma unroll
    for (int c = 0; c < 4; ++c)
      o[c] += *(const f32x4*)&pb[row * 64 + q4 * 16 + c * 4];
    l += pb[4096 + row];
  }
  const int t = qg * 64 + row;
  const float gs = gate[t * 16 + head] / l;
  short* op = ob + (size_t)t * 1024 + head * 64 + q4 * 16;
  #pragma unroll
  for (int c = 0; c < 4; ++c) {
    bf16x4 w;
    w[0] = f2bs(o[c][0] * gs); w[1] = f2bs(o[c][1] * gs);
    w[2] = f2bs(o[c][2] * gs); w[3] = f2bs(o[c][3] * gs);
    *(bf16x4*)&op[c * 4] = w;
  }
}

extern "C" void kernel_launch(void* const* d_in, const int* in_sizes, int n_in,
                              void* d_out, int out_size, void* d_ws, size_t ws_size,
                              hipStream_t stream) {
  const float* x     = (const float*)d_in[0];
  const float* v1    = (const float*)d_in[1];
  const float* Wq    = (const float*)d_in[2];
  const float* Wk    = (const float*)d_in[3];
  const float* Wv    = (const float*)d_in[4];
  const float* Wproj = (const float*)d_in[5];
  const float* lamb  = (const float*)d_in[6];
  const float* Wgate = (const float*)d_in[7];
  float* out = (float*)d_out;

  char* ws = (char*)d_ws;
  short*  xb   = (short*)(ws);                      // 4MB (reused as ob after QKV GEMM)
  short*  wqkv = (short*)(ws + ((size_t)4  << 20)); // 6MB
  short*  wpj  = (short*)(ws + ((size_t)10 << 20)); // 2MB
  float*  Cv   = (float*)(ws + ((size_t)12 << 20)); // 8MB [T][1024] (v proj, f32)
  float*  part = Cv;                                 // 20.3MB, written AFTER Cv consumed
  float2* rope = (float2*)(ws + ((size_t)34 << 20)); // 512KB (above part's 32.3MB end)
  short*  qb   = (short*)(ws + ((size_t)36 << 20)); // 4MB
  short*  kb   = (short*)(ws + ((size_t)40 << 20)); // 4MB
  short*  vt   = (short*)(ws + ((size_t)44 << 20)); // 4MB
  float*  gate = (float*)(ws + ((size_t)48 << 20)); // 128KB
  short*  ob   = xb;

  cvt_all<<<6144, 256, 0, stream>>>(x, Wq, Wk, Wv, Wproj, xb, wqkv, wpj);
  gate_rope<<<(T_SEQ * NH) / 256, 256, 0, stream>>>(x, Wgate, gate, rope);
  gemm64<128, true><<<dim3(32, 24), 256, 0, stream>>>(xb, wqkv, Cv, qb, kb, rope,
                                                      3072, 1024);
  v_blend_tr<<<dim3(T_SEQ / 128, NH), 256, 0, stream>>>(Cv, v1, lamb, vt);
  attn<<<1280, 256, 0, stream>>>(qb, kb, vt, part);
  attn_reduce<<<512, 256, 0, stream>>>(part, gate, ob);
  gemm64<64, false><<<dim3(32, 16), 256, 0, stream>>>(ob, wpj, out, nullptr, nullptr,
                                                      nullptr, 1024, 1024);
  hipMemcpyAsync(out + (size_t)T_SEQ * 1024, v1,
                 (size_t)T_SEQ * 1024 * sizeof(float),
                 hipMemcpyDeviceToDevice, stream);
}

// Round 8
// 116.551 us; speedup vs baseline: 1.0038x; 1.0038x over previous
//
#include <hip/hip_runtime.h>
#include <hip/hip_bf16.h>

#define T_SEQ 2048
#define NH 16
#define HD 64
// 0.1 (attn scale) * log2(e) folded into q at norm time -> softmax uses exp2
#define SCALE_LOG2E 0.14426950408889634f

typedef __attribute__((ext_vector_type(8))) short bf16x8;
typedef __attribute__((ext_vector_type(4))) short bf16x4;
typedef __attribute__((ext_vector_type(4))) float f32x4;

__device__ __forceinline__ short f2bs(float f) {
  union { float f; unsigned u; } v; v.f = f;
  unsigned r = v.u + 0x7fffu + ((v.u >> 16) & 1u);
  return (short)(r >> 16);
}

__device__ __forceinline__ unsigned cvt_pk_bf16(float lo, float hi) {
  unsigned r;
  asm("v_cvt_pk_bf16_f32 %0, %1, %2" : "=v"(r) : "v"(lo), "v"(hi));
  return r;
}

__device__ __forceinline__ void gload16(const short* g, short* l) {
  __builtin_amdgcn_global_load_lds(
      (const __attribute__((address_space(1))) void*)g,
      (__attribute__((address_space(3))) void*)l, 16, 0, 0);
}

// ---------------- fused f32 -> bf16 convert (x, Wq|Wk|Wv, Wproj) ----------------
__global__ __launch_bounds__(256) void cvt_all(const float* __restrict__ x,
                                               const float* __restrict__ wq,
                                               const float* __restrict__ wk,
                                               const float* __restrict__ wv,
                                               const float* __restrict__ wp,
                                               short* __restrict__ xb,
                                               short* __restrict__ wqkv,
                                               short* __restrict__ wpj) {
  size_t i4 = (size_t)(blockIdx.x * 256 + threadIdx.x) * 4;  // over 6M elements
  const int seg = (int)(i4 >> 20);
  const size_t off = i4 & ((1u << 20) - 1);
  const float* src;
  short* dst;
  if (seg < 2)       { src = x + i4;   dst = xb + i4; }
  else if (seg == 2) { src = wq + off; dst = wqkv + off; }
  else if (seg == 3) { src = wk + off; dst = wqkv + (1u << 20) + off; }
  else if (seg == 4) { src = wv + off; dst = wqkv + (2u << 20) + off; }
  else               { src = wp + off; dst = wpj + off; }
  float4 v = *reinterpret_cast<const float4*>(src);
  bf16x4 o; o[0] = f2bs(v.x); o[1] = f2bs(v.y); o[2] = f2bs(v.z); o[3] = f2bs(v.w);
  *reinterpret_cast<bf16x4*>(dst) = o;
}

// -------- gate: sigmoid(x[:, :12] @ Wgate^T); also fills rope table (cos,sin) --------
__global__ __launch_bounds__(256) void gate_rope(const float* __restrict__ x,
                                                 const float* __restrict__ Wg,
                                                 float* __restrict__ gate,
                                                 float2* __restrict__ rope) {
  int id = blockIdx.x * 256 + threadIdx.x;  // t*16 + h, 32768 total
  int t = id >> 4, h = id & 15;
  float acc = 0.f;
  #pragma unroll
  for (int i = 0; i < 12; ++i) acc += x[(size_t)t * 1024 + i] * Wg[h * 12 + i];
  gate[id] = 1.f / (1.f + __expf(-acc));
  // rope[t][p]: 65536 entries, 2 per thread
  #pragma unroll
  for (int j = 0; j < 2; ++j) {
    int e = id * 2 + j;
    int tt = e >> 5, p = e & 31;
    float invf = __builtin_exp2f(-0.41524101186092f * (float)p);
    float s, c;
    sincosf((float)tt * invf, &s, &c);
    rope[e] = make_float2(c, s);
  }
}

// ---------------- GEMM: C[M][N] = A[M][K] * B[N][K]^T (bf16 in) ----------------
// BM=64 x BN tile, BK=32, 4 waves (2x2); TRIPLE-buffered global_load_lds staging with
// COUNTED vmcnt (T4): per wave per step exactly L loads (L=1+BN/64, uniform across
// waves), depth-2 prefetch; s_waitcnt vmcnt(L) at step top waits only the tile being
// consumed while the next stage stays in flight ACROSS the raw s_barrier (never
// drain to 0 in the loop - the round-6 __syncthreads drained vmcnt(0) every step and
// exposed ~300cy/step). Slot reuse safe: stage@k writes slot (k+2)%3=(k-1)%3 whose
// ds_reads completed (consumed by MFMAs) before readers reached barrier k;
// sched_barrier(0) after s_barrier stops ds_read hoisting (rule #18).
// QKV=true: fused epilogue. bn<2048 -> RMSNorm+RoPE -> bf16 qb/kb [h][t][64];
//           bn>=2048 -> plain f32 Cv (cols bn-2048). QKV=false: plain f32 C.
template <int BN, bool QKV>
__global__ __launch_bounds__(256) void gemm64(const short* __restrict__ A,
                                              const short* __restrict__ B,
                                              float* __restrict__ C,
                                              short* __restrict__ qb,
                                              short* __restrict__ kb,
                                              const float2* __restrict__ rope,
                                              int N, int K) {
  constexpr int NB = BN / 32;  // fragments per wave in N
  __shared__ __attribute__((aligned(16))) short As[3][4][64][8];
  __shared__ __attribute__((aligned(16))) short Bs[3][4][BN][8];
  const int tid = threadIdx.x;
  const int lane = tid & 63, wid = tid >> 6;
  const int lr = lane & 15, lg = lane >> 4;
  const int wm = (wid >> 1) * 32, wn = (wid & 1) * (BN / 2);
  const int bm = blockIdx.x * 64, bn = blockIdx.y * BN;
  // wave `wid` stages k-slot `wid` (k offset wid*8)
  const short* Ap = A + (size_t)(bm + lane) * K + wid * 8;
  const short* Bp = B + (size_t)(bn + lane) * K + wid * 8;
  f32x4 acc[2][NB] = {};
  auto stage = [&](int buf, int k0) {
    gload16(Ap + k0, &As[buf][wid][0][0]);
    #pragma unroll
    for (int g = 0; g < BN / 64; ++g)
      gload16(Bp + (size_t)(64 * g) * K + k0, &Bs[buf][wid][64 * g][0]);
  };
  auto compute = [&](int buf) {
    bf16x8 af[2], bfr[NB];
    #pragma unroll
    for (int m = 0; m < 2; ++m) af[m] = *(const bf16x8*)&As[buf][lg][wm + m * 16 + lr][0];
    #pragma unroll
    for (int n = 0; n < NB; ++n) bfr[n] = *(const bf16x8*)&Bs[buf][lg][wn + n * 16 + lr][0];
    #pragma unroll
    for (int m = 0; m < 2; ++m)
      #pragma unroll
      for (int n = 0; n < NB; ++n)
        acc[m][n] = __builtin_amdgcn_mfma_f32_16x16x32_bf16(af[m], bfr[n], acc[m][n], 0, 0, 0);
  };
  const int nsteps = K >> 5;
  stage(0, 0);
  stage(1, 32);
  int cur = 0;
  for (int ks = 0; ks < nsteps - 1; ++ks) {
    // wait only the oldest stage (L loads); the next stage stays in flight
    if constexpr (BN == 128) asm volatile("s_waitcnt vmcnt(3)" ::: "memory");
    else                     asm volatile("s_waitcnt vmcnt(2)" ::: "memory");
    __builtin_amdgcn_s_barrier();
    __builtin_amdgcn_sched_barrier(0);
    int s2 = cur + 2; if (s2 >= 3) s2 -= 3;
    if (ks + 2 < nsteps) stage(s2, (ks + 2) * 32);
    compute(cur);
    cur = (cur == 2) ? 0 : cur + 1;
  }
  asm volatile("s_waitcnt vmcnt(0)" ::: "memory");
  __builtin_amdgcn_s_barrier();
  __builtin_amdgcn_sched_barrier(0);
  compute(cur);

  if constexpr (QKV) {
    if (bn < 2048) {  // q or k head: wave cols = exactly one head
      const bool isq = (bn < 1024);
      short* dst = isq ? qb : kb;
      const int h = ((bn + wn) & 1023) >> 6;
      #pragma unroll
      for (int m = 0; m < 2; ++m)
        #pragma unroll
        for (int r = 0; r < 4; ++r) {
          const int t = bm + wm + m * 16 + 4 * lg + r;
          float ss = acc[m][0][r] * acc[m][0][r] + acc[m][1][r] * acc[m][1][r]
                   + acc[m][2][r] * acc[m][2][r] + acc[m][3][r] * acc[m][3][r];
          ss += __shfl_xor(ss, 1);
          ss += __shfl_xor(ss, 2);
          ss += __shfl_xor(ss, 4);
          ss += __shfl_xor(ss, 8);
          const float rms = rsqrtf(ss * (1.f / 64.f) + 1e-6f);
          short* row = dst + ((size_t)h * T_SEQ + t) * 64;
          #pragma unroll
          for (int n2 = 0; n2 < 2; ++n2) {  // rope pair (d, d+32) = (n2, n2+2)
            float x1 = acc[m][n2][r] * rms, x2 = acc[m][n2 + 2][r] * rms;
            float2 cs = rope[t * 32 + n2 * 16 + lr];
            float y1 = x1 * cs.x + x2 * cs.y;
            float y2 = x2 * cs.x - x1 * cs.y;
            if (isq) { y1 *= SCALE_LOG2E; y2 *= SCALE_LOG2E; }
            row[n2 * 16 + lr] = f2bs(y1);
            row[32 + n2 * 16 + lr] = f2bs(y2);
          }
        }
    } else {  // v region -> plain f32 Cv [t][1024]
      #pragma unroll
      for (int m = 0; m < 2; ++m)
        #pragma unroll
        for (int r = 0; r < 4; ++r) {
          const int t = bm + wm + m * 16 + 4 * lg + r;
          float* Cr = C + (size_t)t * 1024 + (bn - 2048) + wn + lr;
          #pragma unroll
          for (int n = 0; n < NB; ++n) Cr[n * 16] = acc[m][n][r];
        }
    }
  } else {
    #pragma unroll
    for (int m = 0; m < 2; ++m)
      #pragma unroll
      for (int r = 0; r < 4; ++r) {
        const int t = bm + wm + m * 16 + 4 * lg + r;
        float* Cr = C + (size_t)t * N + bn + wn + lr;
        #pragma unroll
        for (int n = 0; n < NB; ++n) Cr[n * 16] = acc[m][n][r];
      }
  }
}

// ---------------- v blend + transpose to vt[h][hd][kv'] (kv permuted per 32-block) ----
// kv' column c within each 32-block holds actual kv = (c&1)*16 + (c>>1), so that
// attention's P-pack (p_t0, p_t1) lands in adjacent columns.
__global__ __launch_bounds__(256) void v_blend_tr(const float* __restrict__ Cv,
                                                  const float* __restrict__ v1,
                                                  const float* __restrict__ lambp,
                                                  short* __restrict__ vt) {
  __shared__ short lv[128][72];
  const int h = blockIdx.y, t0 = blockIdx.x * 128;
  const float lamb = *lambp;
  const int tid = threadIdx.x;
  #pragma unroll 4
  for (int it = 0; it < 32; ++it) {
    int e = it * 256 + tid;
    int tl = e >> 6, d = e & 63;
    float v = Cv[(size_t)(t0 + tl) * 1024 + h * 64 + d];
    float w = v1[(size_t)(t0 + tl) * 1024 + h * 64 + d];
    lv[tl][d] = f2bs((1.f - lamb) * v + lamb * w);
  }
  __syncthreads();
  #pragma unroll 4
  for (int it = 0; it < 32; ++it) {
    int e = it * 256 + tid;
    int d = e >> 7, tl = e & 127;
    int src = (tl & 96) + ((tl & 1) << 4) + ((tl >> 1) & 15);  // permuted source row
    vt[((size_t)h * 64 + d) * T_SEQ + t0 + tl] = lv[src][d];
  }
}

// ---------------- causal attention, split-KV, LDS-staged K/V (double-buffered) -------
// No online max needed (scores bounded by RMS norm): partials over kv strips combine
// by plain addition of accO and lsum -> split-KV grid (head, qgroup64, strip512).
// Partials stored compactly at slot = head*80 + b (b = linear job id 0..79).
__global__ __launch_bounds__(256) void attn(const short* __restrict__ qb,
                                            const short* __restrict__ kb,
                                            const short* __restrict__ vtp,
                                            float* __restrict__ part) {
  __shared__ __attribute__((aligned(16))) short Ks[2][4096];
  __shared__ __attribute__((aligned(16))) short Vs[2][4096];
  __shared__ __attribute__((aligned(16))) short p_lds[4][16][72];
  const int head = blockIdx.x & 15;
  const int b = blockIdx.x >> 4;  // 0..79
  int strip, qg;  // heavy-first (qg descending) within each strip class
  if (b < 32)      { strip = 0; qg = 31 - b; }
  else if (b < 56) { strip = 1; qg = 63 - b; }   // qg 31..8
  else if (b < 72) { strip = 2; qg = 87 - b; }   // qg 31..16
  else             { strip = 3; qg = 103 - b; }  // qg 31..24
  const int nt = min(8, qg + 1 - strip * 8);
  const int lane = threadIdx.x & 63, wid = threadIdx.x >> 6;
  const int lr = lane & 15, lg = lane >> 4;
  const int qt0 = qg * 64 + wid * 16;
  const short* Q = qb + (size_t)head * (T_SEQ * HD);
  const short* Kp = kb + (size_t)head * (T_SEQ * HD);
  const short* Vt = vtp + (size_t)head * (HD * T_SEQ);
  short (*P)[72] = p_lds[wid];

  bf16x8 aq0 = *(const bf16x8*)&Q[(size_t)(qt0 + lr) * HD + 8 * lg];
  bf16x8 aq1 = *(const bf16x8*)&Q[(size_t)(qt0 + lr) * HD + 32 + 8 * lg];
  f32x4 accO[4] = {};
  float lsum[4] = {0.f, 0.f, 0.f, 0.f};

  auto stage = [&](int buf, int jg) {
    const int kv0 = jg * 64;
    #pragma unroll
    for (int i = 0; i < 2; ++i) {
      int s = i * 256 + wid * 64 + lane;       // chunk id 0..511 (16B chunks)
      int row = s >> 3;                        // tile row 0..63
      int cG = (s & 7) ^ (row & 7);            // inverse-swizzled source chunk
      gload16(Kp + (size_t)(kv0 + row) * HD + cG * 8,
              &Ks[buf][(size_t)(i * 256 + wid * 64) * 8]);
      gload16(Vt + (size_t)row * T_SEQ + kv0 + cG * 8,
              &Vs[buf][(size_t)(i * 256 + wid * 64) * 8]);
    }
  };
  stage(0, strip * 8);
  for (int j = 0; j < nt; ++j) {
    const int jg = strip * 8 + j;
    __syncthreads();                            // drains vmcnt: buf[j&1] ready
    if (j + 1 < nt) stage((j + 1) & 1, jg + 1); // prefetch stays in flight
    const short* Kb = Ks[j & 1];
    const short* Vb = Vs[j & 1];
    f32x4 st[4];
    #pragma unroll
    for (int t = 0; t < 4; ++t) {
      int row = 16 * t + lr;
      int c0 = lg ^ (row & 7);
      bf16x8 k0 = *(const bf16x8*)&Kb[row * 64 + c0 * 8];
      bf16x8 k1 = *(const bf16x8*)&Kb[row * 64 + (c0 ^ 4) * 8];
      f32x4 s = {};
      s = __builtin_amdgcn_mfma_f32_16x16x32_bf16(aq0, k0, s, 0, 0, 0);
      s = __builtin_amdgcn_mfma_f32_16x16x32_bf16(aq1, k1, s, 0, 0, 0);
      st[t] = s;
    }
    if (jg == qg) {  // diagonal tile: causal mask (block-uniform branch)
      #pragma unroll
      for (int t = 0; t < 4; ++t)
        #pragma unroll
        for (int r = 0; r < 4; ++r)
          st[t][r] = (16 * t + lr > wid * 16 + 4 * lg + r) ? -1e30f : st[t][r];
    }
    #pragma unroll
    for (int r = 0; r < 4; ++r) {
      float p0 = __builtin_exp2f(st[0][r]);
      float p1 = __builtin_exp2f(st[1][r]);
      float p2 = __builtin_exp2f(st[2][r]);
      float p3 = __builtin_exp2f(st[3][r]);
      lsum[r] += (p0 + p1) + (p2 + p3);
      *(unsigned*)&P[4 * lg + r][2 * lr] = cvt_pk_bf16(p0, p1);
      *(unsigned*)&P[4 * lg + r][32 + 2 * lr] = cvt_pk_bf16(p2, p3);
    }
    asm volatile("s_waitcnt lgkmcnt(0)" ::: "memory");  // wave-private P roundtrip
    __builtin_amdgcn_sched_barrier(0);
    bf16x8 pa0 = *(const bf16x8*)&P[lr][8 * lg];
    bf16x8 pa1 = *(const bf16x8*)&P[lr][32 + 8 * lg];
    #pragma unroll
    for (int nv = 0; nv < 4; ++nv) {
      int row0 = nv * 16 + lr;
      int c0 = lg ^ (row0 & 7);
      bf16x8 v0 = *(const bf16x8*)&Vb[row0 * 64 + c0 * 8];
      bf16x8 v1 = *(const bf16x8*)&Vb[row0 * 64 + (c0 ^ 4) * 8];
      accO[nv] = __builtin_amdgcn_mfma_f32_16x16x32_bf16(pa0, v0, accO[nv], 0, 0, 0);
      accO[nv] = __builtin_amdgcn_mfma_f32_16x16x32_bf16(pa1, v1, accO[nv], 0, 0, 0);
    }
  }
  // write partials: 64x64 O block + 64 lsum, compact slot = head*80 + b
  float* pO = part + (size_t)(head * 80 + b) * 4160;
  float* pL = pO + 4096;
  #pragma unroll
  for (int r = 0; r < 4; ++r) {
    float sres = lsum[r];
    sres += __shfl_xor(sres, 1);
    sres += __shfl_xor(sres, 2);
    sres += __shfl_xor(sres, 4);
    sres += __shfl_xor(sres, 8);
    int row = wid * 16 + 4 * lg + r;
    #pragma unroll
    for (int nv = 0; nv < 4; ++nv)
      pO[row * 64 + nv * 16 + lr] = accO[nv][r];
    if (lr == 0) pL[row] = sres;
  }
}

// ---------------- combine split-KV partials, apply gate, write bf16 ----------------
__global__ __launch_bounds__(256) void attn_reduce(const float* __restrict__ part,
                                                   const float* __restrict__ gate,
                                                   short* __restrict__ ob) {
  const int head = blockIdx.x & 15;
  const int qg = blockIdx.x >> 4;
  const int ns = (qg >> 3) + 1;
  const int tid = threadIdx.x;
  const int row = tid >> 2, q4 = tid & 3;
  const int sbase[4] = {0, 32, 56, 72};  // strip -> b base (b = sbase[s] + 31 - qg)
  f32x4 o[4] = {};
  float l = 0.f;
  for (int s = 0; s < ns; ++s) {
    const float* pb = part + (size_t)(head * 80 + sbase[s] + 31 - qg) * 4160;
    #pragma unroll
    for (int c = 0; c < 4; ++c)
      o[c] += *(const f32x4*)&pb[row * 64 + q4 * 16 + c * 4];
    l += pb[4096 + row];
  }
  const int t = qg * 64 + row;
  const float gs = gate[t * 16 + head] / l;
  short* op = ob + (size_t)t * 1024 + head * 64 + q4 * 16;
  #pragma unroll
  for (int c = 0; c < 4; ++c) {
    bf16x4 w;
    w[0] = f2bs(o[c][0] * gs); w[1] = f2bs(o[c][1] * gs);
    w[2] = f2bs(o[c][2] * gs); w[3] = f2bs(o[c][3] * gs);
    *(bf16x4*)&op[c * 4] = w;
  }
}

extern "C" void kernel_launch(void* const* d_in, const int* in_sizes, int n_in,
                              void* d_out, int out_size, void* d_ws, size_t ws_size,
                              hipStream_t stream) {
  const float* x     = (const float*)d_in[0];
  const float* v1    = (const float*)d_in[1];
  const float* Wq    = (const float*)d_in[2];
  const float* Wk    = (const float*)d_in[3];
  const float* Wv    = (const float*)d_in[4];
  const float* Wproj = (const float*)d_in[5];
  const float* lamb  = (const float*)d_in[6];
  const float* Wgate = (const float*)d_in[7];
  float* out = (float*)d_out;

  char* ws = (char*)d_ws;
  short*  xb   = (short*)(ws);                      // 4MB (reused as ob after QKV GEMM)
  short*  wqkv = (short*)(ws + ((size_t)4  << 20)); // 6MB
  short*  wpj  = (short*)(ws + ((size_t)10 << 20)); // 2MB
  float*  Cv   = (float*)(ws + ((size_t)12 << 20)); // 8MB [T][1024] (v proj, f32)
  float*  part = Cv;                                 // 20.3MB, written AFTER Cv consumed
  float2* rope = (float2*)(ws + ((size_t)34 << 20)); // 512KB (above part's 32.3MB end)
  short*  qb   = (short*)(ws + ((size_t)36 << 20)); // 4MB
  short*  kb   = (short*)(ws + ((size_t)40 << 20)); // 4MB
  short*  vt   = (short*)(ws + ((size_t)44 << 20)); // 4MB
  float*  gate = (float*)(ws + ((size_t)48 << 20)); // 128KB
  short*  ob   = xb;

  cvt_all<<<6144, 256, 0, stream>>>(x, Wq, Wk, Wv, Wproj, xb, wqkv, wpj);
  gate_rope<<<(T_SEQ * NH) / 256, 256, 0, stream>>>(x, Wgate, gate, rope);
  gemm64<128, true><<<dim3(32, 24), 256, 0, stream>>>(xb, wqkv, Cv, qb, kb, rope,
                                                      3072, 1024);
  v_blend_tr<<<dim3(T_SEQ / 128, NH), 256, 0, stream>>>(Cv, v1, lamb, vt);
  attn<<<1280, 256, 0, stream>>>(qb, kb, vt, part);
  attn_reduce<<<512, 256, 0, stream>>>(part, gate, ob);
  gemm64<64, false><<<dim3(32, 16), 256, 0, stream>>>(ob, wpj, out, nullptr, nullptr,
                                                      nullptr, 1024, 1024);
  hipMemcpyAsync(out + (size_t)T_SEQ * 1024, v1,
                 (size_t)T_SEQ * 1024 * sizeof(float),
                 hipMemcpyDeviceToDevice, stream);
}